// Round 1
// baseline (2137.461 us; speedup 1.0000x reference)
//
#include <hip/hip_runtime.h>
#include <math.h>
#include <stdint.h>

// Problem constants (B=1)
#define H 32
#define S 2048
#define D 128
#define SINK 4
#define NOUT 8
#define QMAXF 127.0f

// ---- flat float offsets into d_out (reference tuple order) ----
#define OFF_ATTN   0u
#define OFF_KQUANT 8388608u          // H*S*D
#define OFF_KSCALE 16777216u         // + H*S*D
#define OFF_KSPV   16781312u         // + H*D (=4096)
#define OFF_KSPI   16814080u         // + H*D*8
#define OFF_VQUANT 16846848u         // + H*D*8
#define OFF_VSCALE 25235456u         // + H*S*D
#define OFF_VSPV   25300992u         // + H*S (=65536)
#define OFF_VSPI   25825280u         // + H*S*8
// total = 26349568 floats

// ---------------- helpers ----------------
__device__ inline unsigned long long wave_max_u64(unsigned long long key) {
#pragma unroll
    for (int off = 1; off < 64; off <<= 1) {
        unsigned lo = (unsigned)key, hi = (unsigned)(key >> 32);
        unsigned olo = __shfl_xor(lo, off);
        unsigned ohi = __shfl_xor(hi, off);
        unsigned long long o = ((unsigned long long)ohi << 32) | olo;
        if (o > key) key = o;
    }
    return key;
}

__device__ inline float wave_max_f32(float x) {
#pragma unroll
    for (int off = 1; off < 64; off <<= 1) x = fmaxf(x, __shfl_xor(x, off));
    return x;
}

// ---------------- attention ----------------
// Block = 256 threads (4 waves). Wave handles 32 queries; lane-pair (L, L^1)
// shares one query: lane half = L&1 owns d in [half*64, half*64+64).
// Q held in 64 VGPRs (pre-scaled by 1/sqrt(D)); K/V tiles of 64 keys staged in
// LDS; scores via 64 fma + 1 shfl_xor; online softmax with deferred rescale.
#define QB 128
#define KB 64

__launch_bounds__(256, 2)
__global__ void attn_kernel(const float* __restrict__ Q, const float* __restrict__ K,
                            const float* __restrict__ V, float* __restrict__ O) {
    __shared__ float Klds[KB][D];
    __shared__ float Vlds[KB][D];
    const int h   = blockIdx.y;
    const int qb  = blockIdx.x;
    const int tid = threadIdx.x;
    const int wid  = tid >> 6;
    const int lane = tid & 63;
    const int half = lane & 1;
    const int qw = qb * QB + wid * 32 + (lane >> 1);   // this lane's query row
    const float* Qh = Q + (size_t)h * S * D;
    const float* Kh = K + (size_t)h * S * D;
    const float* Vh = V + (size_t)h * S * D;

    const float scale = 0.08838834764831845f;  // 1/sqrt(128)
    float4 qr[16];
    const float* qptr = Qh + (size_t)qw * D + half * 64;
#pragma unroll
    for (int i = 0; i < 16; ++i) {
        float4 v = *reinterpret_cast<const float4*>(qptr + i * 4);
        qr[i] = make_float4(v.x * scale, v.y * scale, v.z * scale, v.w * scale);
    }
    float4 acc[16];
#pragma unroll
    for (int i = 0; i < 16; ++i) acc[i] = make_float4(0.f, 0.f, 0.f, 0.f);
    float m = -1e30f, l = 0.f;

    const int ntiles = (qb * QB + QB) / KB;            // 2*(qb+1)
    const int qmax_w = qb * QB + wid * 32 + 31;
    for (int t = 0; t < ntiles; ++t) {
        const int k0 = t * KB;
        // cooperative staging: 8192 floats per tensor, 256 threads x 8 float4
#pragma unroll
        for (int i = 0; i < 8; ++i) {
            const int flat = i * 1024 + tid * 4;
            const int r = flat >> 7, c = flat & 127;
            *reinterpret_cast<float4*>(&Klds[r][c]) =
                *reinterpret_cast<const float4*>(Kh + (size_t)(k0 + r) * D + c);
            *reinterpret_cast<float4*>(&Vlds[r][c]) =
                *reinterpret_cast<const float4*>(Vh + (size_t)(k0 + r) * D + c);
        }
        __syncthreads();
        int nk = qmax_w - k0 + 1;
        if (nk > KB) nk = KB;
        for (int k = 0; k < nk; ++k) {
            const float* kr = &Klds[k][half * 64];
            float p0 = 0.f;
#pragma unroll
            for (int i = 0; i < 16; ++i) {
                float4 kv = *reinterpret_cast<const float4*>(kr + i * 4);
                p0 = fmaf(qr[i].x, kv.x, p0);
                p0 = fmaf(qr[i].y, kv.y, p0);
                p0 = fmaf(qr[i].z, kv.z, p0);
                p0 = fmaf(qr[i].w, kv.w, p0);
            }
            float s = p0 + __shfl_xor(p0, 1);          // both halves -> full dot
            s = (k0 + k <= qw) ? s : -1e30f;            // causal mask
            if (__any(s > m + 8.0f)) {                  // deferred rescale (rare)
                const float mn = fmaxf(m, s);
                const float f = __expf(m - mn);
                l *= f;
#pragma unroll
                for (int i = 0; i < 16; ++i) {
                    acc[i].x *= f; acc[i].y *= f; acc[i].z *= f; acc[i].w *= f;
                }
                m = mn;
            }
            const float p = __expf(s - m);              // <= e^8 by construction
            l += p;
            const float* vr = &Vlds[k][half * 64];
#pragma unroll
            for (int i = 0; i < 16; ++i) {
                float4 vv = *reinterpret_cast<const float4*>(vr + i * 4);
                acc[i].x = fmaf(p, vv.x, acc[i].x);
                acc[i].y = fmaf(p, vv.y, acc[i].y);
                acc[i].z = fmaf(p, vv.z, acc[i].z);
                acc[i].w = fmaf(p, vv.w, acc[i].w);
            }
        }
        __syncthreads();
    }
    const float inv = 1.0f / l;
    float* op = O + (size_t)(h * S + qw) * D + half * 64;
#pragma unroll
    for (int i = 0; i < 16; ++i) {
        *reinterpret_cast<float4*>(op + i * 4) =
            make_float4(acc[i].x * inv, acc[i].y * inv, acc[i].z * inv, acc[i].w * inv);
    }
}

// ---------------- K stats: per-(h,d) column top-8 + absmax + scale ----------------
// One wave per column. Lane j holds tokens s = lane + 64*j, j=0..31.
// Extraction order matches jax.lax.top_k: descending |v|, ties -> lower index.
__global__ void k_stats_kernel(const float* __restrict__ K, float* __restrict__ out) {
    const int w = threadIdx.x >> 6, lane = threadIdx.x & 63;
    const int col = blockIdx.x * 4 + w;       // h*128 + d, 0..4095
    const int h = col >> 7, d = col & 127;
    const float* base = K + (size_t)h * S * D + d;
    float v[32];
#pragma unroll
    for (int j = 0; j < 32; ++j) {
        const int s_idx = lane + 64 * j;
        const float x = base[(size_t)s_idx * D];
        v[j] = (s_idx < SINK) ? 0.f : x;
    }
    unsigned done = 0u;
    float spv[NOUT]; int spi[NOUT];
#pragma unroll
    for (int r = 0; r < NOUT; ++r) {
        unsigned best_a = 0u; unsigned best_i = 0x3FFFFFFFu; float best_v = 0.f;
#pragma unroll
        for (int j = 0; j < 32; ++j) {
            const unsigned a = __float_as_uint(v[j]) & 0x7fffffffu;
            // ascending-idx scan with strict '>' keeps the lower index on ties
            const bool better = (!((done >> j) & 1u)) && (a > best_a);
            if (better) { best_a = a; best_i = (unsigned)(lane + 64 * j); best_v = v[j]; }
        }
        const unsigned long long key =
            ((unsigned long long)best_a << 32) | (unsigned)(~best_i);
        const unsigned long long wkey = wave_max_u64(key);
        const int widx = (int)(~(unsigned)wkey);
        const float wval = __shfl(best_v, widx & 63);   // owner's local best == winner
        spv[r] = wval; spi[r] = widx;
        if ((widx & 63) == lane) done |= 1u << (widx >> 6);
    }
    float am = 0.f;
#pragma unroll
    for (int j = 0; j < 32; ++j)
        if (!((done >> j) & 1u)) am = fmaxf(am, fabsf(v[j]));
    am = wave_max_f32(am);
    const float scl = am / QMAXF + 1e-8f;
    if (lane == 0) {
        out[OFF_KSCALE + col] = scl;
#pragma unroll
        for (int r = 0; r < NOUT; ++r) {
            out[OFF_KSPV + (size_t)col * 8 + r] = spv[r];
            out[OFF_KSPI + (size_t)col * 8 + r] = (float)spi[r];
        }
    }
}

// ---------------- K quantize (reads scale/idx back from d_out; same stream) ----------
__global__ void k_quant_kernel(const float* __restrict__ K, float* __restrict__ out) {
    const int gid = blockIdx.x * 256 + threadIdx.x;   // over H*S*D
    const int d = gid & 127;
    const int hs = gid >> 7;
    const int s_idx = hs & (S - 1);
    const int col = ((hs >> 11) << 7) | d;
    const float x = K[gid];
    const float scl = out[OFF_KSCALE + col];
    bool zero = (s_idx < SINK);
#pragma unroll
    for (int r = 0; r < NOUT; ++r)
        zero |= ((int)out[OFF_KSPI + (size_t)col * 8 + r] == s_idx);
    const float dense = zero ? 0.f : x;
    float q = rintf(dense / scl);
    q = fminf(fmaxf(q, -QMAXF), QMAXF);
    out[OFF_KQUANT + (size_t)gid] = q;
}

// ---------------- V: per-(h,s) row top-8 + absmax + quantize, one kernel ----------
__global__ void v_kernel(const float* __restrict__ V, float* __restrict__ out) {
    const int w = threadIdx.x >> 6, lane = threadIdx.x & 63;
    const int row = blockIdx.x * 4 + w;        // h*S + s, 0..65535
    const int s_idx = row & (S - 1);
    const float* base = V + (size_t)row * D;
    float2 vv = *reinterpret_cast<const float2*>(base + lane * 2);
    if (s_idx < SINK) { vv.x = 0.f; vv.y = 0.f; }
    const float v0 = vv.x, v1 = vv.y;
    const unsigned a0 = __float_as_uint(v0) & 0x7fffffffu;
    const unsigned a1 = __float_as_uint(v1) & 0x7fffffffu;
    const unsigned i0 = lane * 2, i1 = lane * 2 + 1;
    unsigned done = 0u;
    float spv[NOUT]; int spi[NOUT];
#pragma unroll
    for (int r = 0; r < NOUT; ++r) {
        const bool e0 = !(done & 1u), e1 = !(done & 2u);
        unsigned best_a, best_i; float best_v;
        if (e1 && (!e0 || a1 > a0)) { best_a = a1; best_i = i1; best_v = v1; }
        else if (e0)                { best_a = a0; best_i = i0; best_v = v0; }
        else                        { best_a = 0u; best_i = 0x3FFFFFFFu; best_v = 0.f; }
        const unsigned long long key =
            ((unsigned long long)best_a << 32) | (unsigned)(~best_i);
        const unsigned long long wkey = wave_max_u64(key);
        const int widx = (int)(~(unsigned)wkey);
        const float cand = (widx & 1) ? v1 : v0;
        const float wval = __shfl(cand, widx >> 1);
        spv[r] = wval; spi[r] = widx;
        if ((widx >> 1) == (int)lane) done |= (widx & 1) ? 2u : 1u;
    }
    float am = fmaxf((done & 1u) ? 0.f : __uint_as_float(a0),
                     (done & 2u) ? 0.f : __uint_as_float(a1));
    am = wave_max_f32(am);
    const float scl = am / QMAXF + 1e-8f;
    const float d0 = (done & 1u) ? 0.f : v0;
    const float d1 = (done & 2u) ? 0.f : v1;
    const float q0 = fminf(fmaxf(rintf(d0 / scl), -QMAXF), QMAXF);
    const float q1 = fminf(fmaxf(rintf(d1 / scl), -QMAXF), QMAXF);
    *reinterpret_cast<float2*>(out + OFF_VQUANT + (size_t)row * D + lane * 2) =
        make_float2(q0, q1);
    if (lane == 0) {
        out[OFF_VSCALE + row] = scl;
#pragma unroll
        for (int r = 0; r < NOUT; ++r) {
            out[OFF_VSPV + (size_t)row * 8 + r] = spv[r];
            out[OFF_VSPI + (size_t)row * 8 + r] = (float)spi[r];
        }
    }
}

// ---------------- launch ----------------
extern "C" void kernel_launch(void* const* d_in, const int* in_sizes, int n_in,
                              void* d_out, int out_size, void* d_ws, size_t ws_size,
                              hipStream_t stream) {
    const float* Q = (const float*)d_in[0];
    const float* K = (const float*)d_in[1];
    const float* V = (const float*)d_in[2];
    float* out = (float*)d_out;

    attn_kernel<<<dim3(S / QB, H), 256, 0, stream>>>(Q, K, V, out + OFF_ATTN);
    k_stats_kernel<<<dim3((H * D) / 4), 256, 0, stream>>>(K, out);
    k_quant_kernel<<<dim3((H * S * D) / 256), 256, 0, stream>>>(K, out);  // after k_stats (same stream)
    v_kernel<<<dim3((H * S) / 4), 256, 0, stream>>>(V, out);
}

// Round 7
// 477.190 us; speedup vs baseline: 4.4793x; 4.4793x over previous
//
#include <hip/hip_runtime.h>
#include <math.h>
#include <stdint.h>

// Problem constants (B=1)
#define H 32
#define S 2048
#define D 128
#define SINK 4
#define NOUT 8
#define QMAXF 127.0f

typedef unsigned short ushort_t;
typedef unsigned int uint_t;

// ---- flat float offsets into d_out (reference tuple order) ----
#define OFF_ATTN   0u
#define OFF_KQUANT 8388608u          // H*S*D
#define OFF_KSCALE 16777216u         // + H*S*D
#define OFF_KSPV   16781312u         // + H*D (=4096)
#define OFF_KSPI   16814080u         // + H*D*8
#define OFF_VQUANT 16846848u         // + H*D*8
#define OFF_VSCALE 25235456u         // + H*S*D
#define OFF_VSPV   25300992u         // + H*S (=65536)
#define OFF_VSPI   25825280u         // + H*S*8

typedef __attribute__((ext_vector_type(8))) short short8;
typedef __attribute__((ext_vector_type(4))) float f32x4;

// ---------------- helpers ----------------
__device__ inline unsigned long long wave_max_u64(unsigned long long key) {
#pragma unroll
    for (int off = 1; off < 64; off <<= 1) {
        unsigned lo = (unsigned)key, hi = (unsigned)(key >> 32);
        unsigned olo = __shfl_xor(lo, off);
        unsigned ohi = __shfl_xor(hi, off);
        unsigned long long o = ((unsigned long long)ohi << 32) | olo;
        if (o > key) key = o;
    }
    return key;
}

__device__ inline float wave_max_f32(float x) {
#pragma unroll
    for (int off = 1; off < 64; off <<= 1) x = fmaxf(x, __shfl_xor(x, off));
    return x;
}

__device__ inline ushort_t bf16rtn(float x) {
    uint_t u = __float_as_uint(x);
    return (ushort_t)((u + 0x7FFFu + ((u >> 16) & 1u)) >> 16);
}

// ---------------- MFMA flash attention ----------------
// Block = 256 threads / 4 waves; block owns 64 queries (wave w: q = qb*64+16w..+15).
// KV tile = 64 keys. Swapped QK^T: S^T frag = mfma(A=K, B=Q) -> lane holds
// col q = lane&15, rows = keys (lane>>4)*4+r per 16-key subtile. Softmax
// lane-local + shfl_xor(16,32). P -> per-wave LDS (bf16) -> A-frags for
// PV = mfma(A=P, B=V^T-staged). All LDS tiles XOR-swizzled to b128-optimal.
__launch_bounds__(256, 2)
__global__ void attn_mfma(const float* __restrict__ Q, const float* __restrict__ K,
                          const float* __restrict__ V, float* __restrict__ O) {
    // K: [64 keys][128 d] bf16, chunk(8 elem/16B) swizzled by row&7
    __shared__ __attribute__((aligned(16))) ushort_t Kh[64 * 128];
    // Vt: [128 dv][64 k] bf16, chunk swizzled by (dv^(dv>>3))&7
    __shared__ __attribute__((aligned(16))) ushort_t Vt[128 * 64];
    // P: per-wave [16 q][64 k] bf16, 8B-chunk swizzled by 2*(q&7)
    __shared__ __attribute__((aligned(16))) ushort_t Pl[4 * 16 * 64];

    const int h   = blockIdx.x;
    const int qb  = (int)gridDim.y - 1 - (int)blockIdx.y;  // heavy blocks first
    const int tid = threadIdx.x;
    const int wid = tid >> 6, lane = tid & 63;
    const int g = lane >> 4, ql = lane & 15;

    const float* Qh = Q + (size_t)h * S * D;
    const float* Kg = K + (size_t)h * S * D;
    const float* Vg = V + (size_t)h * S * D;

    const int wq0 = qb * 64 + wid * 16;
    const int qg  = wq0 + ql;                 // this lane's q in the S-phase
    const float sc = 0.08838834764831845f;    // 1/sqrt(128)

    // Q B-frags: B[32d][16q]: lane holds col q=ql, d = dt*32 + g*8 + j
    short8 qf[4];
#pragma unroll
    for (int dt = 0; dt < 4; ++dt) {
        const float* qp = Qh + (size_t)qg * D + dt * 32 + g * 8;
        float4 a = *(const float4*)qp;
        float4 b = *(const float4*)(qp + 4);
        float f[8] = {a.x, a.y, a.z, a.w, b.x, b.y, b.z, b.w};
        union { ushort_t us[8]; short8 v; } u;
#pragma unroll
        for (int j = 0; j < 8; ++j) u.us[j] = bf16rtn(f[j] * sc);
        qf[dt] = u.v;
    }

    f32x4 acc[8];
#pragma unroll
    for (int i = 0; i < 8; ++i) acc[i] = (f32x4){0.f, 0.f, 0.f, 0.f};
    float m = -1e30f, l = 0.f;

    const int ntiles = qb + 1;
    for (int t = 0; t < ntiles; ++t) {
        const int k0 = t * 64;
        __syncthreads();
        // ---- stage K (bf16, swizzled) ----
#pragma unroll
        for (int i = 0; i < 4; ++i) {
            const int flat = i * 256 + tid;
            const int row = flat >> 4, c = flat & 15;
            const float* kp = Kg + (size_t)(k0 + row) * D + c * 8;
            float4 a = *(const float4*)kp;
            float4 b = *(const float4*)(kp + 4);
            float f[8] = {a.x, a.y, a.z, a.w, b.x, b.y, b.z, b.w};
            union { ushort_t us[8]; uint4 u4; } u;
#pragma unroll
            for (int j = 0; j < 8; ++j) u.us[j] = bf16rtn(f[j]);
            *(uint4*)&Kh[(row * 16 + (c ^ (row & 7))) * 8] = u.u4;
        }
        // ---- stage V transposed (bf16 k-pairs, swizzled) ----
        uint_t* VtU = (uint_t*)Vt;
#pragma unroll
        for (int uu = 0; uu < 2; ++uu) {
            const int p = (tid >> 4) + 16 * uu;
            const int c = tid & 15;
            const float* v0 = Vg + (size_t)(k0 + 2 * p) * D + c * 8;
            const float* v1 = v0 + D;
            float4 a0 = *(const float4*)v0, b0 = *(const float4*)(v0 + 4);
            float4 a1 = *(const float4*)v1, b1 = *(const float4*)(v1 + 4);
            float r0[8] = {a0.x, a0.y, a0.z, a0.w, b0.x, b0.y, b0.z, b0.w};
            float r1[8] = {a1.x, a1.y, a1.z, a1.w, b1.x, b1.y, b1.z, b1.w};
#pragma unroll
            for (int i = 0; i < 8; ++i) {
                const int dv = 8 * c + i;
                const int sv = (dv ^ (dv >> 3)) & 7;
                const uint_t pk = (uint_t)bf16rtn(r0[i]) | ((uint_t)bf16rtn(r1[i]) << 16);
                VtU[dv * 32 + (((p >> 2) ^ sv) << 2) + (p & 3)] = pk;
            }
        }
        __syncthreads();

        // ---- QK^T (swapped): S^T[key][q] ----
        f32x4 sf[4];
#pragma unroll
        for (int st = 0; st < 4; ++st) {
            f32x4 a = (f32x4){0.f, 0.f, 0.f, 0.f};
#pragma unroll
            for (int dt = 0; dt < 4; ++dt) {
                const short8 kf =
                    *(const short8*)&Kh[((16 * st + ql) * 16 + ((g + 4 * dt) ^ (ql & 7))) * 8];
                a = __builtin_amdgcn_mfma_f32_16x16x32_bf16(kf, qf[dt], a, 0, 0, 0);
            }
            sf[st] = a;
        }
        // ---- causal mask (only near the diagonal) ----
        if (k0 + 63 > wq0) {
#pragma unroll
            for (int st = 0; st < 4; ++st)
#pragma unroll
                for (int r = 0; r < 4; ++r) {
                    const int key = k0 + 16 * st + 4 * g + r;
                    if (key > qg) sf[st][r] = -1e30f;
                }
        }
        // ---- online softmax (deferred rescale, THR=8) ----
        float tm = sf[0][0];
#pragma unroll
        for (int st = 0; st < 4; ++st)
#pragma unroll
            for (int r = 0; r < 4; ++r) tm = fmaxf(tm, sf[st][r]);
        tm = fmaxf(tm, __shfl_xor(tm, 16));
        tm = fmaxf(tm, __shfl_xor(tm, 32));
        if (__any(tm > m + 8.0f)) {
            const float mn = fmaxf(m, tm);
            const float f = __expf(m - mn);
            l *= f;
            float fr[4];
#pragma unroll
            for (int r = 0; r < 4; ++r) fr[r] = __shfl(f, g * 4 + r);
#pragma unroll
            for (int i = 0; i < 8; ++i)
#pragma unroll
                for (int r = 0; r < 4; ++r) acc[i][r] *= fr[r];
            m = mn;
        }
        float ts = 0.f;
        uint2* PlU = (uint2*)Pl;
#pragma unroll
        for (int st = 0; st < 4; ++st) {
            float p0 = __expf(sf[st][0] - m);
            float p1 = __expf(sf[st][1] - m);
            float p2 = __expf(sf[st][2] - m);
            float p3 = __expf(sf[st][3] - m);
            ts += (p0 + p1) + (p2 + p3);
            uint2 w;
            w.x = (uint_t)bf16rtn(p0) | ((uint_t)bf16rtn(p1) << 16);
            w.y = (uint_t)bf16rtn(p2) | ((uint_t)bf16rtn(p3) << 16);
            PlU[wid * 256 + ql * 16 + ((4 * st + g) ^ (2 * (ql & 7)))] = w;
        }
        ts += __shfl_xor(ts, 16);
        ts += __shfl_xor(ts, 32);
        l += ts;

        // ---- PV: O[q][dv] += P[q][k] * V[k][dv] ----
        short8 pa[2];
#pragma unroll
        for (int ks = 0; ks < 2; ++ks)
            pa[ks] = *(const short8*)&Pl[(wid * 128 + ql * 8 + ((4 * ks + g) ^ (ql & 7))) * 8];
#pragma unroll
        for (int dvt = 0; dvt < 8; ++dvt) {
            const int dv = dvt * 16 + ql;
            const int sv = (dv ^ (dv >> 3)) & 7;
#pragma unroll
            for (int ks = 0; ks < 2; ++ks) {
                const short8 vf = *(const short8*)&Vt[(dv * 8 + ((g + 4 * ks) ^ sv)) * 8];
                acc[dvt] = __builtin_amdgcn_mfma_f32_16x16x32_bf16(pa[ks], vf, acc[dvt], 0, 0, 0);
            }
        }
    }

    // ---- epilogue: normalize rows q' = wq0 + g*4 + r, store ----
    float inv[4];
#pragma unroll
    for (int r = 0; r < 4; ++r) {
        const float lr = __shfl(l, g * 4 + r);
        inv[r] = 1.0f / lr;
    }
#pragma unroll
    for (int dvt = 0; dvt < 8; ++dvt)
#pragma unroll
        for (int r = 0; r < 4; ++r) {
            const int qq = wq0 + g * 4 + r;
            O[(size_t)(h * S + qq) * D + dvt * 16 + ql] = acc[dvt][r] * inv[r];
        }
}

// ---------------- K stats: per-(h,d) column top-8 + absmax + scale ----------------
__global__ void k_stats_kernel(const float* __restrict__ K, float* __restrict__ out) {
    const int w = threadIdx.x >> 6, lane = threadIdx.x & 63;
    const int col = blockIdx.x * 4 + w;       // h*128 + d
    const int h = col >> 7, d = col & 127;
    const float* base = K + (size_t)h * S * D + d;
    float v[32];
#pragma unroll
    for (int j = 0; j < 32; ++j) {
        const int s_idx = lane + 64 * j;
        const float x = base[(size_t)s_idx * D];
        v[j] = (s_idx < SINK) ? 0.f : x;
    }
    unsigned done = 0u;
    float spv[NOUT]; int spi[NOUT];
#pragma unroll
    for (int r = 0; r < NOUT; ++r) {
        unsigned best_a = 0u; unsigned best_i = 0x3FFFFFFFu; float best_v = 0.f;
#pragma unroll
        for (int j = 0; j < 32; ++j) {
            const unsigned a = __float_as_uint(v[j]) & 0x7fffffffu;
            const bool better = (!((done >> j) & 1u)) && (a > best_a);
            if (better) { best_a = a; best_i = (unsigned)(lane + 64 * j); best_v = v[j]; }
        }
        const unsigned long long key =
            ((unsigned long long)best_a << 32) | (unsigned)(~best_i);
        const unsigned long long wkey = wave_max_u64(key);
        const int widx = (int)(~(unsigned)wkey);
        const float wval = __shfl(best_v, widx & 63);
        spv[r] = wval; spi[r] = widx;
        if ((widx & 63) == lane) done |= 1u << (widx >> 6);
    }
    float am = 0.f;
#pragma unroll
    for (int j = 0; j < 32; ++j)
        if (!((done >> j) & 1u)) am = fmaxf(am, fabsf(v[j]));
    am = wave_max_f32(am);
    const float scl = am / QMAXF + 1e-8f;
    if (lane == 0) {
        out[OFF_KSCALE + col] = scl;
#pragma unroll
        for (int r = 0; r < NOUT; ++r) {
            out[OFF_KSPV + (size_t)col * 8 + r] = spv[r];
            out[OFF_KSPI + (size_t)col * 8 + r] = (float)spi[r];
        }
    }
}

// ---------------- K quantize ----------------
__global__ void k_quant_kernel(const float* __restrict__ K, float* __restrict__ out) {
    const int gid = blockIdx.x * 256 + threadIdx.x;
    const int d = gid & 127;
    const int hs = gid >> 7;
    const int s_idx = hs & (S - 1);
    const int col = ((hs >> 11) << 7) | d;
    const float x = K[gid];
    const float scl = out[OFF_KSCALE + col];
    bool zero = (s_idx < SINK);
#pragma unroll
    for (int r = 0; r < NOUT; ++r)
        zero |= ((int)out[OFF_KSPI + (size_t)col * 8 + r] == s_idx);
    const float dense = zero ? 0.f : x;
    float q = rintf(dense / scl);
    q = fminf(fmaxf(q, -QMAXF), QMAXF);
    out[OFF_KQUANT + (size_t)gid] = q;
}

// ---------------- V: per-(h,s) row top-8 + absmax + quantize ----------------
__global__ void v_kernel(const float* __restrict__ V, float* __restrict__ out) {
    const int w = threadIdx.x >> 6, lane = threadIdx.x & 63;
    const int row = blockIdx.x * 4 + w;
    const int s_idx = row & (S - 1);
    const float* base = V + (size_t)row * D;
    float2 vv = *reinterpret_cast<const float2*>(base + lane * 2);
    if (s_idx < SINK) { vv.x = 0.f; vv.y = 0.f; }
    const float v0 = vv.x, v1 = vv.y;
    const unsigned a0 = __float_as_uint(v0) & 0x7fffffffu;
    const unsigned a1 = __float_as_uint(v1) & 0x7fffffffu;
    const unsigned i0 = lane * 2, i1 = lane * 2 + 1;
    unsigned done = 0u;
    float spv[NOUT]; int spi[NOUT];
#pragma unroll
    for (int r = 0; r < NOUT; ++r) {
        const bool e0 = !(done & 1u), e1 = !(done & 2u);
        unsigned best_a, best_i; float best_v;
        if (e1 && (!e0 || a1 > a0)) { best_a = a1; best_i = i1; best_v = v1; }
        else if (e0)                { best_a = a0; best_i = i0; best_v = v0; }
        else                        { best_a = 0u; best_i = 0x3FFFFFFFu; best_v = 0.f; }
        const unsigned long long key =
            ((unsigned long long)best_a << 32) | (unsigned)(~best_i);
        const unsigned long long wkey = wave_max_u64(key);
        const int widx = (int)(~(unsigned)wkey);
        const float cand = (widx & 1) ? v1 : v0;
        const float wval = __shfl(cand, widx >> 1);
        spv[r] = wval; spi[r] = widx;
        if ((widx >> 1) == (int)lane) done |= (widx & 1) ? 2u : 1u;
    }
    float am = fmaxf((done & 1u) ? 0.f : __uint_as_float(a0),
                     (done & 2u) ? 0.f : __uint_as_float(a1));
    am = wave_max_f32(am);
    const float scl = am / QMAXF + 1e-8f;
    const float d0 = (done & 1u) ? 0.f : v0;
    const float d1 = (done & 2u) ? 0.f : v1;
    const float q0 = fminf(fmaxf(rintf(d0 / scl), -QMAXF), QMAXF);
    const float q1 = fminf(fmaxf(rintf(d1 / scl), -QMAXF), QMAXF);
    *reinterpret_cast<float2*>(out + OFF_VQUANT + (size_t)row * D + lane * 2) =
        make_float2(q0, q1);
    if (lane == 0) {
        out[OFF_VSCALE + row] = scl;
#pragma unroll
        for (int r = 0; r < NOUT; ++r) {
            out[OFF_VSPV + (size_t)row * 8 + r] = spv[r];
            out[OFF_VSPI + (size_t)row * 8 + r] = (float)spi[r];
        }
    }
}

// ---------------- launch ----------------
extern "C" void kernel_launch(void* const* d_in, const int* in_sizes, int n_in,
                              void* d_out, int out_size, void* d_ws, size_t ws_size,
                              hipStream_t stream) {
    const float* Q = (const float*)d_in[0];
    const float* K = (const float*)d_in[1];
    const float* V = (const float*)d_in[2];
    float* out = (float*)d_out;

    attn_mfma<<<dim3(H, S / 64), 256, 0, stream>>>(Q, K, V, out + OFF_ATTN);
    k_stats_kernel<<<dim3((H * D) / 4), 256, 0, stream>>>(K, out);
    k_quant_kernel<<<dim3((H * S * D) / 256), 256, 0, stream>>>(K, out);  // after k_stats
    v_kernel<<<dim3((H * S) / 4), 256, 0, stream>>>(V, out);
}

// Round 9
// 458.861 us; speedup vs baseline: 4.6582x; 1.0399x over previous
//
#include <hip/hip_runtime.h>
#include <math.h>
#include <stdint.h>

// Problem constants (B=1)
#define H 32
#define S 2048
#define D 128
#define SINK 4
#define NOUT 8
#define QMAXF 127.0f

typedef unsigned short ushort_t;
typedef unsigned int uint_t;

// ---- flat float offsets into d_out (reference tuple order) ----
#define OFF_ATTN   0u
#define OFF_KQUANT 8388608u          // H*S*D
#define OFF_KSCALE 16777216u         // + H*S*D
#define OFF_KSPV   16781312u         // + H*D (=4096)
#define OFF_KSPI   16814080u         // + H*D*8
#define OFF_VQUANT 16846848u         // + H*D*8
#define OFF_VSCALE 25235456u         // + H*S*D
#define OFF_VSPV   25300992u         // + H*S (=65536)
#define OFF_VSPI   25825280u         // + H*S*8

typedef __attribute__((ext_vector_type(8))) short short8;
typedef __attribute__((ext_vector_type(4))) float f32x4;

// ---------------- helpers ----------------
__device__ inline unsigned long long wave_max_u64(unsigned long long key) {
#pragma unroll
    for (int off = 1; off < 64; off <<= 1) {
        unsigned lo = (unsigned)key, hi = (unsigned)(key >> 32);
        unsigned olo = __shfl_xor(lo, off);
        unsigned ohi = __shfl_xor(hi, off);
        unsigned long long o = ((unsigned long long)ohi << 32) | olo;
        if (o > key) key = o;
    }
    return key;
}

__device__ inline float wave_max_f32(float x) {
#pragma unroll
    for (int off = 1; off < 64; off <<= 1) x = fmaxf(x, __shfl_xor(x, off));
    return x;
}

__device__ inline ushort_t bf16rtn(float x) {
    uint_t u = __float_as_uint(x);
    return (ushort_t)((u + 0x7FFFu + ((u >> 16) & 1u)) >> 16);
}

// ---------------- MFMA flash attention (UNCHANGED — control) ----------------
__launch_bounds__(256, 2)
__global__ void attn_mfma(const float* __restrict__ Q, const float* __restrict__ K,
                          const float* __restrict__ V, float* __restrict__ O) {
    __shared__ __attribute__((aligned(16))) ushort_t Kh[64 * 128];
    __shared__ __attribute__((aligned(16))) ushort_t Vt[128 * 64];
    __shared__ __attribute__((aligned(16))) ushort_t Pl[4 * 16 * 64];

    const int h   = blockIdx.x;
    const int qb  = (int)gridDim.y - 1 - (int)blockIdx.y;  // heavy blocks first
    const int tid = threadIdx.x;
    const int wid = tid >> 6, lane = tid & 63;
    const int g = lane >> 4, ql = lane & 15;

    const float* Qh = Q + (size_t)h * S * D;
    const float* Kg = K + (size_t)h * S * D;
    const float* Vg = V + (size_t)h * S * D;

    const int wq0 = qb * 64 + wid * 16;
    const int qg  = wq0 + ql;
    const float sc = 0.08838834764831845f;  // 1/sqrt(128)

    short8 qf[4];
#pragma unroll
    for (int dt = 0; dt < 4; ++dt) {
        const float* qp = Qh + (size_t)qg * D + dt * 32 + g * 8;
        float4 a = *(const float4*)qp;
        float4 b = *(const float4*)(qp + 4);
        float f[8] = {a.x, a.y, a.z, a.w, b.x, b.y, b.z, b.w};
        union { ushort_t us[8]; short8 v; } u;
#pragma unroll
        for (int j = 0; j < 8; ++j) u.us[j] = bf16rtn(f[j] * sc);
        qf[dt] = u.v;
    }

    f32x4 acc[8];
#pragma unroll
    for (int i = 0; i < 8; ++i) acc[i] = (f32x4){0.f, 0.f, 0.f, 0.f};
    float m = -1e30f, l = 0.f;

    const int ntiles = qb + 1;
    for (int t = 0; t < ntiles; ++t) {
        const int k0 = t * 64;
        __syncthreads();
#pragma unroll
        for (int i = 0; i < 4; ++i) {
            const int flat = i * 256 + tid;
            const int row = flat >> 4, c = flat & 15;
            const float* kp = Kg + (size_t)(k0 + row) * D + c * 8;
            float4 a = *(const float4*)kp;
            float4 b = *(const float4*)(kp + 4);
            float f[8] = {a.x, a.y, a.z, a.w, b.x, b.y, b.z, b.w};
            union { ushort_t us[8]; uint4 u4; } u;
#pragma unroll
            for (int j = 0; j < 8; ++j) u.us[j] = bf16rtn(f[j]);
            *(uint4*)&Kh[(row * 16 + (c ^ (row & 7))) * 8] = u.u4;
        }
        uint_t* VtU = (uint_t*)Vt;
#pragma unroll
        for (int uu = 0; uu < 2; ++uu) {
            const int p = (tid >> 4) + 16 * uu;
            const int c = tid & 15;
            const float* v0 = Vg + (size_t)(k0 + 2 * p) * D + c * 8;
            const float* v1 = v0 + D;
            float4 a0 = *(const float4*)v0, b0 = *(const float4*)(v0 + 4);
            float4 a1 = *(const float4*)v1, b1 = *(const float4*)(v1 + 4);
            float r0[8] = {a0.x, a0.y, a0.z, a0.w, b0.x, b0.y, b0.z, b0.w};
            float r1[8] = {a1.x, a1.y, a1.z, a1.w, b1.x, b1.y, b1.z, b1.w};
#pragma unroll
            for (int i = 0; i < 8; ++i) {
                const int dv = 8 * c + i;
                const int sv = (dv ^ (dv >> 3)) & 7;
                const uint_t pk = (uint_t)bf16rtn(r0[i]) | ((uint_t)bf16rtn(r1[i]) << 16);
                VtU[dv * 32 + (((p >> 2) ^ sv) << 2) + (p & 3)] = pk;
            }
        }
        __syncthreads();

        f32x4 sf[4];
#pragma unroll
        for (int st = 0; st < 4; ++st) {
            f32x4 a = (f32x4){0.f, 0.f, 0.f, 0.f};
#pragma unroll
            for (int dt = 0; dt < 4; ++dt) {
                const short8 kf =
                    *(const short8*)&Kh[((16 * st + ql) * 16 + ((g + 4 * dt) ^ (ql & 7))) * 8];
                a = __builtin_amdgcn_mfma_f32_16x16x32_bf16(kf, qf[dt], a, 0, 0, 0);
            }
            sf[st] = a;
        }
        if (k0 + 63 > wq0) {
#pragma unroll
            for (int st = 0; st < 4; ++st)
#pragma unroll
                for (int r = 0; r < 4; ++r) {
                    const int key = k0 + 16 * st + 4 * g + r;
                    if (key > qg) sf[st][r] = -1e30f;
                }
        }
        float tm = sf[0][0];
#pragma unroll
        for (int st = 0; st < 4; ++st)
#pragma unroll
            for (int r = 0; r < 4; ++r) tm = fmaxf(tm, sf[st][r]);
        tm = fmaxf(tm, __shfl_xor(tm, 16));
        tm = fmaxf(tm, __shfl_xor(tm, 32));
        if (__any(tm > m + 8.0f)) {
            const float mn = fmaxf(m, tm);
            const float f = __expf(m - mn);
            l *= f;
            float fr[4];
#pragma unroll
            for (int r = 0; r < 4; ++r) fr[r] = __shfl(f, g * 4 + r);
#pragma unroll
            for (int i = 0; i < 8; ++i)
#pragma unroll
                for (int r = 0; r < 4; ++r) acc[i][r] *= fr[r];
            m = mn;
        }
        float ts = 0.f;
        uint2* PlU = (uint2*)Pl;
#pragma unroll
        for (int st = 0; st < 4; ++st) {
            float p0 = __expf(sf[st][0] - m);
            float p1 = __expf(sf[st][1] - m);
            float p2 = __expf(sf[st][2] - m);
            float p3 = __expf(sf[st][3] - m);
            ts += (p0 + p1) + (p2 + p3);
            uint2 w;
            w.x = (uint_t)bf16rtn(p0) | ((uint_t)bf16rtn(p1) << 16);
            w.y = (uint_t)bf16rtn(p2) | ((uint_t)bf16rtn(p3) << 16);
            PlU[wid * 256 + ql * 16 + ((4 * st + g) ^ (2 * (ql & 7)))] = w;
        }
        ts += __shfl_xor(ts, 16);
        ts += __shfl_xor(ts, 32);
        l += ts;

        short8 pa[2];
#pragma unroll
        for (int ks = 0; ks < 2; ++ks)
            pa[ks] = *(const short8*)&Pl[(wid * 128 + ql * 8 + ((4 * ks + g) ^ (ql & 7))) * 8];
#pragma unroll
        for (int dvt = 0; dvt < 8; ++dvt) {
            const int dv = dvt * 16 + ql;
            const int sv = (dv ^ (dv >> 3)) & 7;
#pragma unroll
            for (int ks = 0; ks < 2; ++ks) {
                const short8 vf = *(const short8*)&Vt[(dv * 8 + ((g + 4 * ks) ^ sv)) * 8];
                acc[dvt] = __builtin_amdgcn_mfma_f32_16x16x32_bf16(pa[ks], vf, acc[dvt], 0, 0, 0);
            }
        }
    }

    float inv[4];
#pragma unroll
    for (int r = 0; r < 4; ++r) {
        const float lr = __shfl(l, g * 4 + r);
        inv[r] = 1.0f / lr;
    }
#pragma unroll
    for (int dvt = 0; dvt < 8; ++dvt)
#pragma unroll
        for (int r = 0; r < 4; ++r) {
            const int qq = wq0 + g * 4 + r;
            O[(size_t)(h * S + qq) * D + dvt * 16 + ql] = acc[dvt][r] * inv[r];
        }
}

// ---------------- K stats: coalesced LDS-transposed column top-8 ----------------
// Block = 512 thr / 8 waves = 8 adjacent columns (d0 8-aligned). Two phases:
// stage [1024 s x 8 d] coalesced into LDS (XOR-swizzled), wave w reads its
// column's 16 tokens/lane conflict-free, then the verified top-8 scan runs
// unchanged (v[j] <-> s = lane + 64*j preserved). Also publishes a per-(h,s)
// outlier bitmask into d_ws for k_quant.
__launch_bounds__(512, 2)
__global__ void k_stats_kernel(const float* __restrict__ K, float* __restrict__ out,
                               uint_t* __restrict__ mask) {
    __shared__ float Tile[8 * 1024];   // 32 KB
    const int tid = threadIdx.x;
    const int w = tid >> 6, lane = tid & 63;
    const int h  = blockIdx.x >> 4;          // 16 blocks per head
    const int d0 = (blockIdx.x & 15) * 8;
    const int d  = d0 + w;
    const int col = h * 128 + d;
    const float* Kh = K + (size_t)h * S * D + d0;

    float v[32];
#pragma unroll
    for (int ph = 0; ph < 2; ++ph) {
        __syncthreads();
#pragma unroll
        for (int i = 0; i < 16; ++i) {
            const int flat = i * 512 + tid;          // 0..8191
            const int s = flat >> 3, c = flat & 7;
            Tile[c * 1024 + (s ^ (c << 2))] = Kh[(size_t)(ph * 1024 + s) * D + c];
        }
        __syncthreads();
#pragma unroll
        for (int j = 0; j < 16; ++j) {
            const int sl = lane + 64 * j;
            const float x = Tile[w * 1024 + (sl ^ (w << 2))];
            const int s_idx = ph * 1024 + sl;
            v[ph * 16 + j] = (s_idx < SINK) ? 0.f : x;
        }
    }

    unsigned done = 0u;
    float spv[NOUT]; int spi[NOUT];
#pragma unroll
    for (int r = 0; r < NOUT; ++r) {
        unsigned best_a = 0u; unsigned best_i = 0x3FFFFFFFu; float best_v = 0.f;
#pragma unroll
        for (int j = 0; j < 32; ++j) {
            const unsigned a = __float_as_uint(v[j]) & 0x7fffffffu;
            const bool better = (!((done >> j) & 1u)) && (a > best_a);
            if (better) { best_a = a; best_i = (unsigned)(lane + 64 * j); best_v = v[j]; }
        }
        const unsigned long long key =
            ((unsigned long long)best_a << 32) | (unsigned)(~best_i);
        const unsigned long long wkey = wave_max_u64(key);
        const int widx = (int)(~(unsigned)wkey);
        const float wval = __shfl(best_v, widx & 63);
        spv[r] = wval; spi[r] = widx;
        if ((widx & 63) == lane) done |= 1u << (widx >> 6);
    }
    float am = 0.f;
#pragma unroll
    for (int j = 0; j < 32; ++j)
        if (!((done >> j) & 1u)) am = fmaxf(am, fabsf(v[j]));
    am = wave_max_f32(am);
    const float scl = am / QMAXF + 1e-8f;
    if (lane == 0) {
        out[OFF_KSCALE + col] = scl;
#pragma unroll
        for (int r = 0; r < NOUT; ++r) {
            out[OFF_KSPV + (size_t)col * 8 + r] = spv[r];
            out[OFF_KSPI + (size_t)col * 8 + r] = (float)spi[r];
            const int s = spi[r];
            if (s >= 0 && s < S)                       // sentinel guard
                atomicOr(&mask[(((size_t)h * S + s) << 2) + (d >> 5)], 1u << (d & 31));
        }
    }
}

// ---------------- K quantize: bitmask + coalesced scale ----------------
__global__ void k_quant_kernel(const float* __restrict__ K, float* __restrict__ out,
                               const uint_t* __restrict__ mask) {
    const int gid = blockIdx.x * 256 + threadIdx.x;
    const int d = gid & 127;
    const int hs = gid >> 7;
    const int s_idx = hs & (S - 1);
    const int col = ((hs >> 11) << 7) | d;
    const float x = K[gid];
    const uint_t wm = mask[((size_t)hs << 2) + (d >> 5)];   // 2 addrs per wave
    const bool zero = (s_idx < SINK) || ((wm >> (d & 31)) & 1u);
    const float scl = out[OFF_KSCALE + col];                // coalesced, L2-hot
    const float dense = zero ? 0.f : x;
    float q = rintf(dense / scl);
    q = fminf(fmaxf(q, -QMAXF), QMAXF);
    out[OFF_KQUANT + (size_t)gid] = q;
}

// ---------------- V: per-(h,s) row top-8 + absmax + quantize (UNCHANGED) ------
__global__ void v_kernel(const float* __restrict__ V, float* __restrict__ out) {
    const int w = threadIdx.x >> 6, lane = threadIdx.x & 63;
    const int row = blockIdx.x * 4 + w;
    const int s_idx = row & (S - 1);
    const float* base = V + (size_t)row * D;
    float2 vv = *reinterpret_cast<const float2*>(base + lane * 2);
    if (s_idx < SINK) { vv.x = 0.f; vv.y = 0.f; }
    const float v0 = vv.x, v1 = vv.y;
    const unsigned a0 = __float_as_uint(v0) & 0x7fffffffu;
    const unsigned a1 = __float_as_uint(v1) & 0x7fffffffu;
    const unsigned i0 = lane * 2, i1 = lane * 2 + 1;
    unsigned done = 0u;
    float spv[NOUT]; int spi[NOUT];
#pragma unroll
    for (int r = 0; r < NOUT; ++r) {
        const bool e0 = !(done & 1u), e1 = !(done & 2u);
        unsigned best_a, best_i; float best_v;
        if (e1 && (!e0 || a1 > a0)) { best_a = a1; best_i = i1; best_v = v1; }
        else if (e0)                { best_a = a0; best_i = i0; best_v = v0; }
        else                        { best_a = 0u; best_i = 0x3FFFFFFFu; best_v = 0.f; }
        const unsigned long long key =
            ((unsigned long long)best_a << 32) | (unsigned)(~best_i);
        const unsigned long long wkey = wave_max_u64(key);
        const int widx = (int)(~(unsigned)wkey);
        const float cand = (widx & 1) ? v1 : v0;
        const float wval = __shfl(cand, widx >> 1);
        spv[r] = wval; spi[r] = widx;
        if ((widx >> 1) == (int)lane) done |= (widx & 1) ? 2u : 1u;
    }
    float am = fmaxf((done & 1u) ? 0.f : __uint_as_float(a0),
                     (done & 2u) ? 0.f : __uint_as_float(a1));
    am = wave_max_f32(am);
    const float scl = am / QMAXF + 1e-8f;
    const float d0 = (done & 1u) ? 0.f : v0;
    const float d1 = (done & 2u) ? 0.f : v1;
    const float q0 = fminf(fmaxf(rintf(d0 / scl), -QMAXF), QMAXF);
    const float q1 = fminf(fmaxf(rintf(d1 / scl), -QMAXF), QMAXF);
    *reinterpret_cast<float2*>(out + OFF_VQUANT + (size_t)row * D + lane * 2) =
        make_float2(q0, q1);
    if (lane == 0) {
        out[OFF_VSCALE + row] = scl;
#pragma unroll
        for (int r = 0; r < NOUT; ++r) {
            out[OFF_VSPV + (size_t)row * 8 + r] = spv[r];
            out[OFF_VSPI + (size_t)row * 8 + r] = (float)spi[r];
        }
    }
}

// ---------------- launch ----------------
extern "C" void kernel_launch(void* const* d_in, const int* in_sizes, int n_in,
                              void* d_out, int out_size, void* d_ws, size_t ws_size,
                              hipStream_t stream) {
    const float* Q = (const float*)d_in[0];
    const float* K = (const float*)d_in[1];
    const float* V = (const float*)d_in[2];
    float* out = (float*)d_out;
    uint_t* mask = (uint_t*)d_ws;                     // H*S*D bits = 1 MB

    hipMemsetAsync(d_ws, 0, (size_t)H * S * D / 8, stream);
    attn_mfma<<<dim3(H, S / 64), 256, 0, stream>>>(Q, K, V, out + OFF_ATTN);
    k_stats_kernel<<<dim3((H * D) / 8), 512, 0, stream>>>(K, out, mask);
    k_quant_kernel<<<dim3((H * S * D) / 256), 256, 0, stream>>>(K, out, mask);
    v_kernel<<<dim3((H * S) / 4), 256, 0, stream>>>(V, out);
}